// Round 9
// baseline (214.258 us; speedup 1.0000x reference)
//
#include <hip/hip_runtime.h>
#include <hip/hip_cooperative_groups.h>
#include <math.h>

namespace cg = cooperative_groups;

#define PH 7
#define PW 7
#define B_ 4
#define C_ 256
#define H_ 50
#define W_ 50
#define R_ 256
#define S_ (H_ * W_)     // 2500
#define NCELL (PH * PW)  // 49
#define MAXW 9           // max window width: ceil(50/7)+1
#define LDSP 129         // [49][128] tile stride; 129%32==1 -> conflict-free
#define GRID 512
#define THREADS 256
#define NWAVES (GRID * (THREADS / 64))   // 2048

__device__ __forceinline__ float4 max4(float4 a, float4 b) {
    a.x = fmaxf(a.x, b.x); a.y = fmaxf(a.y, b.y);
    a.z = fmaxf(a.z, b.z); a.w = fmaxf(a.w, b.w);
    return a;
}

// ONE cooperative dispatch containing the three proven phases of the round-3
// pipeline (90.1 us), separated by grid.sync() instead of kernel boundaries.
// R2 measured single-dispatch overhead ~6 us vs ~24 us of gaps for 4
// dispatches — the phases themselves are unchanged (K1 3.3 / K2 9.2 / K3 ~5).
// Residency: 512 blk x 256 thr, VGPR<=128 (bounds 256,4) -> 16 waves/CU cap,
// LDS 25.3 KB -> 6 blk/CU cap; need only 2 blk/CU. All phases reuse one LDS.
__global__ void __launch_bounds__(THREADS, 4)
roi_all(const float* __restrict__ features, const int* __restrict__ rois,
        float* __restrict__ out, float* __restrict__ ft,
        float* __restrict__ tmp) {
    __shared__ float lds[NCELL * LDSP];   // 25.3 KB; phase A reuses first 1 KB
    const int tid  = threadIdx.x;
    const int wid  = tid >> 6;            // 0..3
    const int lane = tid & 63;

    // ---------- phase A: features (B,C,H,W) -> ft (B,H,W,C) ----------
    // Round-0/3 K1 tiles (32x32, pad 33), virtualized over 512 blocks.
    {
        float (*tile)[33] = (float (*)[33])lds;
        const int tx = tid & 31, ty = tid >> 5;      // 32 x 8 layout
        const int NSB = (S_ + 31) / 32;              // 79 s-tiles
        const int NVT = NSB * 8 * B_;                // 2528 virtual tiles
        for (int vt = blockIdx.x; vt < NVT; vt += GRID) {
            const int bb  = vt / (NSB * 8);
            const int rem = vt - bb * (NSB * 8);
            const int cb  = rem / NSB;
            const int sb  = rem - cb * NSB;
            const int s0 = sb * 32, c0 = cb * 32;
            const float* inb  = features + (size_t)bb * C_ * S_;
            float*       outb = ft       + (size_t)bb * S_ * C_;
            #pragma unroll
            for (int i = ty; i < 32; i += 8) {
                const int s = s0 + tx;
                if (s < S_) tile[i][tx] = inb[(size_t)(c0 + i) * S_ + s];
            }
            __syncthreads();
            #pragma unroll
            for (int i = ty; i < 32; i += 8) {
                const int s = s0 + i;
                if (s < S_) outb[(size_t)s * C_ + (c0 + tx)] = tile[tx][i];
            }
            __syncthreads();                         // tile reused next iter
        }
    }

    cg::this_grid().sync();

    // ---------- phase B: pool. unit = (roi, cell), R3-K2 inner loop ----------
    // u -> (r = u/49, cell = u%49); wave stride 2048 advances r by ~41:
    // a wave's 6-7 units hit DIFFERENT rois -> big-roi work scatters across
    // waves (the tail imbalance that sank R1/R8 fusions can't form).
    {
        const int gw = blockIdx.x * (THREADS / 64) + wid;   // 0..2047
        for (int u = gw; u < R_ * NCELL; u += NWAVES) {
            const int r    = u / NCELL;        // const divisor -> magic mul
            const int cell = u - r * NCELL;

            const int* roi = rois + r * 5;     // wave-uniform scalar loads
            const int b  = roi[0];
            const int x1 = roi[1] >> 4;        // floor(v/16), v >= 0
            const int y1 = roi[2] >> 4;
            const int x2 = roi[3] >> 4;
            const int y2 = roi[4] >> 4;
            const int h = y2 - y1 + 1;
            const int w = x2 - x1 + 1;

            const int ph = cell / PW;
            const int pw = cell - ph * PW;
            const int sh = y1 + (ph * h) / PH;
            const int eh = y1 + ((ph + 1) * h + PH - 1) / PH;
            const int sw = x1 + (pw * w) / PW;
            const int ew = x1 + ((pw + 1) * w + PW - 1) / PW;
            const int kw = ew - sw;            // 1..9, wave-uniform

            const float* fb = ft + (size_t)b * S_ * C_ + 4 * lane;

            float4 acc = make_float4(-INFINITY, -INFINITY, -INFINITY, -INFINITY);

            int y = sh;
            if ((eh - sh) & 1) {               // odd band height: single row
                const float* p0 = fb + (size_t)(y * W_ + sw) * C_;
                float4 v0[MAXW];
                #pragma unroll
                for (int k = 0; k < MAXW; ++k)
                    if (k < kw) v0[k] = *(const float4*)(p0 + (size_t)k * C_);
                #pragma unroll
                for (int k = 0; k < MAXW; ++k)
                    if (k < kw) acc = max4(acc, v0[k]);
                ++y;
            }
            for (; y < eh; y += 2) {           // even remainder: row pairs
                const float* p0 = fb + (size_t)( y      * W_ + sw) * C_;
                const float* p1 = fb + (size_t)((y + 1) * W_ + sw) * C_;
                float4 v0[MAXW], v1[MAXW];
                #pragma unroll
                for (int k = 0; k < MAXW; ++k) {
                    if (k < kw) {              // wave-uniform branch
                        v0[k] = *(const float4*)(p0 + (size_t)k * C_);
                        v1[k] = *(const float4*)(p1 + (size_t)k * C_);
                    }
                }
                #pragma unroll
                for (int k = 0; k < MAXW; ++k) {
                    if (k < kw) acc = max4(acc, max4(v0[k], v1[k]));
                }
            }

            *(float4*)(tmp + ((size_t)(r * NCELL + cell)) * C_ + 4 * lane) = acc;
        }
    }

    cg::this_grid().sync();

    // ---------- phase C: tmp (R,49,C) -> out (R,C,49), R3-K3 1:1 ----------
    {
        const int r  = blockIdx.x >> 1;
        const int c0 = (blockIdx.x & 1) << 7;      // 0 or 128
        const float* src = tmp + (size_t)r * NCELL * C_ + c0;
        float*       dst = out + (size_t)r * C_ * NCELL + (size_t)c0 * NCELL;

        #pragma unroll
        for (int i = tid; i < NCELL * 128; i += THREADS) {
            const int cell = i >> 7;               // i = cell*128 + c
            const int c    = i & 127;
            lds[cell * LDSP + c] = src[(size_t)cell * C_ + c];
        }
        __syncthreads();
        #pragma unroll
        for (int f = tid; f < 128 * NCELL; f += THREADS) {
            const int c    = f / NCELL;            // magic mul
            const int cell = f - c * NCELL;        // f = c*49 + cell
            dst[f] = lds[cell * LDSP + c];
        }
    }
}

extern "C" void kernel_launch(void* const* d_in, const int* in_sizes, int n_in,
                              void* d_out, int out_size, void* d_ws, size_t ws_size,
                              hipStream_t stream) {
    const float* features = (const float*)d_in[0];
    const int*   rois     = (const int*)d_in[1];
    float*       out      = (float*)d_out;

    float* ft  = (float*)d_ws;                       // 10.24 MB
    float* tmp = ft + (size_t)B_ * S_ * C_;          // +12.85 MB (ws is 256 MB)

    void* args[] = { (void*)&features, (void*)&rois, (void*)&out,
                     (void*)&ft, (void*)&tmp };
    hipLaunchCooperativeKernel((const void*)roi_all, dim3(GRID), dim3(THREADS),
                               args, 0, stream);
}

// Round 10
// 88.894 us; speedup vs baseline: 2.4103x; 2.4103x over previous
//
#include <hip/hip_runtime.h>
#include <math.h>

#define PH 7
#define PW 7
#define B_ 4
#define C_ 256
#define H_ 50
#define W_ 50
#define R_ 256
#define S_ (H_ * W_)     // 2500
#define NCELL (PH * PW)  // 49
#define MAXW 9           // max window width: ceil(50/7)+1
#define THREADS 448      // 7 waves = 7 cells (one ph-row)

// ---------- kernel 1: features (B,C,H,W) -> (B,H,W,C) ----------
__global__ void transpose_chw_hwc(const float* __restrict__ in, float* __restrict__ out) {
    __shared__ float tile[32][33];
    const int b  = blockIdx.z;
    const int s0 = blockIdx.x * 32;
    const int c0 = blockIdx.y * 32;
    const float* inb  = in  + (size_t)b * C_ * S_;
    float*       outb = out + (size_t)b * S_ * C_;
    const int tx = threadIdx.x;
    #pragma unroll
    for (int i = threadIdx.y; i < 32; i += 8) {
        const int s = s0 + tx;
        if (s < S_) tile[i][tx] = inb[(size_t)(c0 + i) * S_ + s];
    }
    __syncthreads();
    #pragma unroll
    for (int i = threadIdx.y; i < 32; i += 8) {
        const int s = s0 + i;
        if (s < S_) outb[(size_t)s * C_ + (c0 + tx)] = tile[tx][i];
    }
}

__device__ __forceinline__ float4 max4(float4 a, float4 b) {
    a.x = fmaxf(a.x, b.x); a.y = fmaxf(a.y, b.y);
    a.z = fmaxf(a.z, b.z); a.w = fmaxf(a.w, b.w);
    return a;
}

// ---------- kernel 2 (fused pool + output write): block = (roi, ph-row) ----
// 7 waves; wave pw computes ONE cell with the R3-proven inner loop (float4
// per lane, 1 KB coalesced loads, 2 rows in flight) — serial chain per wave
// unchanged. 1792 blocks (~7 rounds/CU) so big-roi tails amortize (the
// R1/R8 fusion killer). Results staged in linear LDS [c*7+pw] (7 KB):
// write phase reads stride-1 (conflict-free) and stores 7-consecutive-cell
// chunks (28 B segments, stride 196 B) -> out (R,C,49) directly.
// Eliminates kernel 3 and its dispatch gap + the 25.7 MB tmp round-trip.
__global__ void __launch_bounds__(THREADS, 4)
roi_pool_row(const float* __restrict__ ft, const int* __restrict__ rois,
             float* __restrict__ out) {
    __shared__ float lds[C_ * PW];        // [c][pw] at c*7+pw, 7168 B
    const int bx   = blockIdx.x;
    const int r    = bx / PH;             // 0..255 (magic mul)
    const int ph   = bx - r * PH;         // 0..6
    const int pw   = threadIdx.x >> 6;    // 0..6 (wave id = cell col)
    const int lane = threadIdx.x & 63;

    const int* roi = rois + r * 5;
    const int b  = roi[0];
    const int x1 = roi[1] >> 4;   // floor(v/16), v >= 0
    const int y1 = roi[2] >> 4;
    const int x2 = roi[3] >> 4;
    const int y2 = roi[4] >> 4;
    const int h = y2 - y1 + 1;
    const int w = x2 - x1 + 1;

    const int sh = y1 + (ph * h) / PH;
    const int eh = y1 + ((ph + 1) * h + PH - 1) / PH;
    const int sw = x1 + (pw * w) / PW;
    const int ew = x1 + ((pw + 1) * w + PW - 1) / PW;
    const int kw = ew - sw;               // 1..9, wave-uniform

    const float* fb = ft + (size_t)b * S_ * C_ + 4 * lane;

    float4 acc = make_float4(-INFINITY, -INFINITY, -INFINITY, -INFINITY);

    int y = sh;
    if ((eh - sh) & 1) {                  // odd band height: single-row prologue
        const float* p0 = fb + (size_t)(y * W_ + sw) * C_;
        float4 v0[MAXW];
        #pragma unroll
        for (int k = 0; k < MAXW; ++k)
            if (k < kw) v0[k] = *(const float4*)(p0 + (size_t)k * C_);
        #pragma unroll
        for (int k = 0; k < MAXW; ++k)
            if (k < kw) acc = max4(acc, v0[k]);
        ++y;
    }
    for (; y < eh; y += 2) {              // even remainder: true row pairs
        const float* p0 = fb + (size_t)( y      * W_ + sw) * C_;
        const float* p1 = fb + (size_t)((y + 1) * W_ + sw) * C_;
        float4 v0[MAXW], v1[MAXW];
        #pragma unroll
        for (int k = 0; k < MAXW; ++k) {
            if (k < kw) {                 // wave-uniform branch
                v0[k] = *(const float4*)(p0 + (size_t)k * C_);
                v1[k] = *(const float4*)(p1 + (size_t)k * C_);
            }
        }
        #pragma unroll
        for (int k = 0; k < MAXW; ++k) {
            if (k < kw) acc = max4(acc, max4(v0[k], v1[k]));
        }
    }

    // stage: lds[c*7 + pw], c = 4*lane+j  (8-way bank alias on writes: ~free,
    // 4 ds_writes per wave total)
    lds[(4 * lane + 0) * PW + pw] = acc.x;
    lds[(4 * lane + 1) * PW + pw] = acc.y;
    lds[(4 * lane + 2) * PW + pw] = acc.z;
    lds[(4 * lane + 3) * PW + pw] = acc.w;

    __syncthreads();

    // out (R,C,49): this block owns cells [7*ph, 7*ph+7) for all 256 ch.
    // idx = c*7+k -> LDS read stride-1 (conflict-free); global: 7-float
    // chunks at stride 49 (28 B segments — semi-coalesced).
    float* dst = out + (size_t)r * C_ * NCELL + 7 * ph;
    #pragma unroll
    for (int idx = threadIdx.x; idx < C_ * PW; idx += THREADS) {
        const int c = idx / PW;           // magic mul
        const int k = idx - c * PW;
        dst[(size_t)c * NCELL + k] = lds[idx];
    }
}

extern "C" void kernel_launch(void* const* d_in, const int* in_sizes, int n_in,
                              void* d_out, int out_size, void* d_ws, size_t ws_size,
                              hipStream_t stream) {
    const float* features = (const float*)d_in[0];
    const int*   rois     = (const int*)d_in[1];
    float*       out      = (float*)d_out;

    float* ft = (float*)d_ws;                        // 10.24 MB (ws is 256 MB)

    dim3 tgrid((S_ + 31) / 32, C_ / 32, B_);
    transpose_chw_hwc<<<tgrid, dim3(32, 8), 0, stream>>>(features, ft);
    roi_pool_row<<<R_ * PH, THREADS, 0, stream>>>(ft, rois, out);
}